// Round 7
// baseline (1701.577 us; speedup 1.0000x reference)
//
#include <hip/hip_runtime.h>
#include <cstdint>
#include <cstddef>

// Problem constants (match reference)
#define N_ROWS 65536
#define K_CODES 4096
#define DIM 512
#define ND_OUT ((size_t)N_ROWS * DIM)   // 33554432

typedef __attribute__((ext_vector_type(8))) short  short8v;   // 8 x bf16 (4 VGPR)
typedef __attribute__((ext_vector_type(4))) float  f32x4;

// ---------------- d_ws layout (bytes) ----------------
#define WS_PACKED   0u            // u64[N]
#define WS_SSUM     524288u       // f32[N]
#define WS_AVGP     786432u       // f32[K]
#define WS_ARN      802816u       // f32[N]
#define WS_BRN      1064960u      // f32[K]
#define WS_PLANES   2097152ull    // bf16 planes: Ah | Al | Bh | Bl (contiguous)
#define SZ_APLANE   67108864ull   // N*512*2
#define SZ_BPLANE   4194304ull    // K*512*2
#define NEED_B      (WS_PLANES + 2*SZ_APLANE + 2*SZ_BPLANE)   // 144703488

// plane offsets in bf16 elements, relative to planes base
#define PE_AH 0
#define PE_AL 33554432
#define PE_BH 67108864
#define PE_BL 69206016

#define GLOAD_LDS16(gsrc, ldst) \
  __builtin_amdgcn_global_load_lds((const __attribute__((address_space(1))) void*)(gsrc), \
                                   (__attribute__((address_space(3))) void*)(ldst), 16, 0, 0)

__device__ inline unsigned long long pack_max(float v, unsigned idx) {
    unsigned u = __float_as_uint(v);
    u = (u & 0x80000000u) ? ~u : (u | 0x80000000u);
    return ((unsigned long long)u << 32) | (unsigned)(~idx);  // tie -> smaller idx wins
}

__device__ inline ushort bf16rn(float f) {
    unsigned u = __float_as_uint(f);
    u += 0x7FFFu + ((u >> 16) & 1u);
    return (ushort)(u >> 16);
}
__device__ inline float bf16f(ushort h) { return __uint_as_float((unsigned)h << 16); }

// ---------------- fused norm + hi/lo split (one wave per row) ----------------
__global__ __launch_bounds__(256) void norm_split(const float* __restrict__ x,
                                                  ushort* __restrict__ hi,
                                                  ushort* __restrict__ lo,
                                                  float* __restrict__ nrm,
                                                  const float* __restrict__ scale_ptr) {
    int lane = threadIdx.x & 63;
    int row  = blockIdx.x * 4 + (threadIdx.x >> 6);
    const float4* x4 = reinterpret_cast<const float4*>(x) + (size_t)row * (DIM / 4);
    float4 v0 = x4[lane];
    float4 v1 = x4[64 + lane];
    float s = v0.x*v0.x + v0.y*v0.y + v0.z*v0.z + v0.w*v0.w
            + v1.x*v1.x + v1.y*v1.y + v1.z*v1.z + v1.w*v1.w;
#pragma unroll
    for (int off = 32; off; off >>= 1) s += __shfl_xor(s, off);

    ushort4 h0, l0, h1, l1;
    h0.x = bf16rn(v0.x); l0.x = bf16rn(v0.x - bf16f(h0.x));
    h0.y = bf16rn(v0.y); l0.y = bf16rn(v0.y - bf16f(h0.y));
    h0.z = bf16rn(v0.z); l0.z = bf16rn(v0.z - bf16f(h0.z));
    h0.w = bf16rn(v0.w); l0.w = bf16rn(v0.w - bf16f(h0.w));
    h1.x = bf16rn(v1.x); l1.x = bf16rn(v1.x - bf16f(h1.x));
    h1.y = bf16rn(v1.y); l1.y = bf16rn(v1.y - bf16f(h1.y));
    h1.z = bf16rn(v1.z); l1.z = bf16rn(v1.z - bf16f(h1.z));
    h1.w = bf16rn(v1.w); l1.w = bf16rn(v1.w - bf16f(h1.w));
    ushort4* hi4 = reinterpret_cast<ushort4*>(hi) + (size_t)row * (DIM / 4);
    ushort4* lo4 = reinterpret_cast<ushort4*>(lo) + (size_t)row * (DIM / 4);
    hi4[lane] = h0; hi4[64 + lane] = h1;
    lo4[lane] = l0; lo4[64 + lane] = l1;

    if (lane == 0) {
        float scale = scale_ptr ? scale_ptr[0] : 1.0f;
        nrm[row] = scale / fmaxf(sqrtf(s), 1e-12f);
    }
}

// ---------------- PASS 1: full-reuse compensated GEMM, single-barrier overlapped step ----
// Tile 256x256, 512 thr = 8 waves (4 wr x 2 wc), wave-tile 64x128, BK=32 per K-step.
// LDS: 4 sub-slots x 32KB ring (2 steps of hi/lo pairs). Step t reads pair t&1,
// stages step t+1 into pair (t+1)&1 (slots last read at t-1; WAR-safe after barrier t).
// Step schedule (ONE barrier per step):
//   vmcnt(0)  [retires stage(t), issued a full step ago -> free]; s_barrier
//   ds_read ah(4), bh(8); lgkmcnt(0)
//   stage(t+1) [8 global_load_lds]
//   ds_read bl(8), al(4)          <- issued BEFORE hh so LDS pipe runs under MFMA
//   MFMA hh(32)
//   lgkmcnt(4) [bl ready]; MFMA hl(32)
//   lgkmcnt(0) [al ready]; MFMA lh(32); ll(32)
__global__ __launch_bounds__(512, 2) void mfma4(
        const ushort* __restrict__ planes,
        const float* __restrict__ arn, const float* __restrict__ brn,
        unsigned long long* __restrict__ packed, float* __restrict__ ssum) {
    __shared__ __align__(16) char lds[131072];
    char* const R0 = lds;
    char* const R1 = lds + 32768;
    char* const R2 = lds + 65536;
    char* const R3 = lds + 98304;

    const int tid  = threadIdx.x;
    const int lane = tid & 63;
    const int wavei = __builtin_amdgcn_readfirstlane(tid >> 6);
    const int wr = wavei >> 1, wc = wavei & 1;
    const int r16 = lane & 15, kg = lane >> 4;

    // XCD swizzle (nwg=4096 %8==0), identical to rounds 3/4/6
    const int orig = blockIdx.x;
    const int swz  = (orig & 7) * 512 + (orig >> 3);
    const int row0 = (swz >> 4) * 256, col0 = (swz & 15) * 256;

    // staging: 4 units (1KB = 64 lanes x 16B) per wave per sub-slot
    size_t rowoff[4];
    int ldso[4];
    bool uA[4];
#pragma unroll
    for (int j = 0; j < 4; ++j) {
        int u = wavei * 4 + j;        // 0..31: units 0-15 = A, 16-31 = B
        bool a = (u < 16);
        int g0 = a ? row0 : col0;
        rowoff[j] = (size_t)(g0 + (u & 15) * 16 + r16) * DIM + kg * 8;
        ldso[j] = u * 1024;
        uA[j] = a;
    }

#define STAGE_HI(KK, DST)                                                              \
    { _Pragma("unroll")                                                                \
      for (int j = 0; j < 4; ++j)                                                      \
          GLOAD_LDS16(planes + (uA[j] ? PE_AH : PE_BH) + rowoff[j] + (KK),             \
                      (DST) + ldso[j]); }
#define STAGE_LO(KK, DST)                                                              \
    { _Pragma("unroll")                                                                \
      for (int j = 0; j < 4; ++j)                                                      \
          GLOAD_LDS16(planes + (uA[j] ? PE_AL : PE_BL) + rowoff[j] + (KK),             \
                      (DST) + ldso[j]); }

    f32x4 acc[4][8];
#pragma unroll
    for (int m = 0; m < 4; ++m)
#pragma unroll
        for (int n = 0; n < 8; ++n) acc[m][n] = f32x4{0.f, 0.f, 0.f, 0.f};

#define MFMA32(AV, BV)                                                                 \
    _Pragma("unroll")                                                                  \
    for (int m_ = 0; m_ < 4; ++m_)                                                     \
        _Pragma("unroll")                                                              \
        for (int n_ = 0; n_ < 8; ++n_)                                                 \
            acc[m_][n_] = __builtin_amdgcn_mfma_f32_16x16x32_bf16((AV)[m_], (BV)[n_],  \
                                                                  acc[m_][n_], 0, 0, 0);

#define STEP(HI, LO, HI2, LO2, KNEXT, DOSTAGE)                                         \
    {                                                                                  \
        short8v ah_[4], bh_[8], bl_[8], al_[4];                                        \
        /* slot pair (t) ready once every wave's own stage loads retired + barrier */  \
        asm volatile("s_waitcnt vmcnt(0)" ::: "memory");                               \
        asm volatile("s_barrier" ::: "memory");                                        \
        __builtin_amdgcn_sched_barrier(0);                                             \
        _Pragma("unroll")                                                              \
        for (int m = 0; m < 4; ++m)                                                    \
            ah_[m] = *(const short8v*)((HI) + (wr * 4 + m) * 1024 + lane * 16);        \
        _Pragma("unroll")                                                              \
        for (int n = 0; n < 8; ++n)                                                    \
            bh_[n] = *(const short8v*)((HI) + 16384 + (wc * 8 + n) * 1024 + lane * 16);\
        asm volatile("s_waitcnt lgkmcnt(0)" ::: "memory");                             \
        __builtin_amdgcn_sched_barrier(0);                                             \
        if (DOSTAGE) { STAGE_HI((KNEXT) * 32, HI2); STAGE_LO((KNEXT) * 32, LO2); }     \
        /* prefetch lo-plane frags; LDS pipe serves these under the hh MFMA */         \
        _Pragma("unroll")                                                              \
        for (int n = 0; n < 8; ++n)                                                    \
            bl_[n] = *(const short8v*)((LO) + 16384 + (wc * 8 + n) * 1024 + lane * 16);\
        _Pragma("unroll")                                                              \
        for (int m = 0; m < 4; ++m)                                                    \
            al_[m] = *(const short8v*)((LO) + (wr * 4 + m) * 1024 + lane * 16);        \
        __builtin_amdgcn_sched_barrier(0);                                             \
        __builtin_amdgcn_s_setprio(1);                                                 \
        MFMA32(ah_, bh_);                                                              \
        __builtin_amdgcn_s_setprio(0);                                                 \
        asm volatile("s_waitcnt lgkmcnt(4)" ::: "memory");                             \
        __builtin_amdgcn_sched_barrier(0);                                             \
        __builtin_amdgcn_s_setprio(1);                                                 \
        MFMA32(ah_, bl_);                                                              \
        __builtin_amdgcn_s_setprio(0);                                                 \
        asm volatile("s_waitcnt lgkmcnt(0)" ::: "memory");                             \
        __builtin_amdgcn_sched_barrier(0);                                             \
        __builtin_amdgcn_s_setprio(1);                                                 \
        MFMA32(al_, bh_);                                                              \
        MFMA32(al_, bl_);                                                              \
        __builtin_amdgcn_s_setprio(0);                                                 \
        __builtin_amdgcn_sched_barrier(0);                                             \
    }

    // prologue: stage step 0 into R0/R1 (one-time exposed latency at t=0)
    STAGE_HI(0, R0);
    STAGE_LO(0, R1);

#pragma unroll 1
    for (int t = 0; t < 14; t += 2) {
        STEP(R0, R1, R2, R3, t + 1, 1);   // even step: read pair{0,1}, stage pair{2,3}
        STEP(R2, R3, R0, R1, t + 2, 1);   // odd  step: read pair{2,3}, stage pair{0,1}
    }
    STEP(R0, R1, R2, R3, 15, 1);          // t=14: stages step 15 -> R2,R3
    STEP(R2, R3, R0, R1, 0, 0);           // t=15: no stage
#undef STEP
#undef MFMA32
#undef STAGE_HI
#undef STAGE_LO

    // ---------------- epilogue: argmax + sumexp ----------------
    const int g = lane >> 4, c15 = lane & 15;
    float bc[8];
#pragma unroll
    for (int n = 0; n < 8; ++n) bc[n] = brn[col0 + wc * 128 + n * 16 + c15];

#pragma unroll
    for (int m = 0; m < 4; ++m)
#pragma unroll
        for (int rr = 0; rr < 4; ++rr) {
            const int grow = row0 + wr * 64 + m * 16 + g * 4 + rr;
            const float ar = arn[grow];
            float mx = -1e30f; int mi = 0; float se = 0.f;
#pragma unroll
            for (int n = 0; n < 8; ++n) {
                float lg = acc[m][n][rr] * ar * bc[n];
                int gcol = col0 + wc * 128 + n * 16 + c15;
                se += __expf(lg);
                if (lg > mx || (lg == mx && gcol < mi)) { mx = lg; mi = gcol; }
            }
#pragma unroll
            for (int off = 1; off < 16; off <<= 1) {
                float om = __shfl_xor(mx, off, 16);
                int   oi = __shfl_xor(mi, off, 16);
                float os = __shfl_xor(se, off, 16);
                se += os;
                if (om > mx || (om == mx && oi < mi)) { mx = om; mi = oi; }
            }
            if (c15 == 0) {
                atomicMax(packed + grow, pack_max(mx, (unsigned)mi));
                atomicAdd(&ssum[grow], se);
            }
        }
}

// ---------------- PASS 2: hh-only counted-vmcnt 4-slot pipeline (round-4, proven) ----------------
template <int EPI, int NREG>
__global__ __launch_bounds__(512, 2) void mfma3(
        const ushort* __restrict__ planes,
        const float* __restrict__ arn, const float* __restrict__ brn,
        unsigned long long* __restrict__ packed, float* __restrict__ ssum,
        float* __restrict__ avgp) {
    constexpr int NSTEPS = NREG * 16;
    __shared__ __align__(16) char lds[131072];

    const int tid  = threadIdx.x;
    const int lane = tid & 63;
    const int wavei = __builtin_amdgcn_readfirstlane(tid >> 6);
    const int wr = wavei >> 1, wc = wavei & 1;
    const int r16 = lane & 15, kg = lane >> 4;

    const int orig = blockIdx.x;
    const int swz  = (orig & 7) * 512 + (orig >> 3);
    const int row0 = (swz >> 4) * 256, col0 = (swz & 15) * 256;

    size_t rowoff[4];
    int ldso[4];
    bool uA[4];
#pragma unroll
    for (int j = 0; j < 4; ++j) {
        int u = wavei * 4 + j;
        bool a = (u < 16);
        int g0 = a ? row0 : col0;
        rowoff[j] = (size_t)(g0 + (u & 15) * 16 + r16) * DIM + kg * 8;
        ldso[j] = u * 1024;
        uA[j] = a;
    }

    auto STAGE = [&](int ks, char* slot) {
        int rg  = (ks >> 4) & 3;
        int kk  = (ks & 15) * 32;
        int bA = (rg & 1) ? PE_AL : PE_AH;
        int bB = ((rg ^ (rg >> 1)) & 1) ? PE_BL : PE_BH;
#pragma unroll
        for (int j = 0; j < 4; ++j) {
            const ushort* src = planes + (uA[j] ? bA : bB) + kk + rowoff[j];
            GLOAD_LDS16(src, slot + ldso[j]);
        }
    };

    f32x4 acc[4][8];
#pragma unroll
    for (int m = 0; m < 4; ++m)
#pragma unroll
        for (int n = 0; n < 8; ++n) acc[m][n] = f32x4{0.f, 0.f, 0.f, 0.f};

    char* const S0 = lds;
    char* const S1 = lds + 32768;
    char* const S2 = lds + 65536;
    char* const S3 = lds + 98304;

#define KSTEP(CUR, NXT, KS, DO_STAGE, VMC)                                              \
    do {                                                                                \
        short8v a_[4], b_[8];                                                           \
        _Pragma("unroll")                                                               \
        for (int m = 0; m < 4; ++m)                                                     \
            a_[m] = *(const short8v*)((CUR) + (wr * 4 + m) * 1024 + lane * 16);         \
        _Pragma("unroll")                                                               \
        for (int n = 0; n < 8; ++n)                                                     \
            b_[n] = *(const short8v*)((CUR) + 16384 + (wc * 8 + n) * 1024 + lane * 16); \
        asm volatile("s_waitcnt lgkmcnt(0)" ::: "memory");                              \
        if (DO_STAGE) STAGE((KS), (NXT));                                               \
        asm volatile("s_waitcnt vmcnt(" #VMC ")" ::: "memory");                         \
        asm volatile("s_barrier" ::: "memory");                                         \
        __builtin_amdgcn_sched_barrier(0);                                              \
        __builtin_amdgcn_s_setprio(1);                                                  \
        _Pragma("unroll")                                                               \
        for (int m = 0; m < 4; ++m)                                                     \
            _Pragma("unroll")                                                           \
            for (int n = 0; n < 8; ++n)                                                 \
                acc[m][n] = __builtin_amdgcn_mfma_f32_16x16x32_bf16(a_[m], b_[n],       \
                                                                    acc[m][n], 0, 0, 0);\
        __builtin_amdgcn_s_setprio(0);                                                  \
        __builtin_amdgcn_sched_barrier(0);                                              \
    } while (0)

    STAGE(0, S0);
    STAGE(1, S1);
    asm volatile("s_waitcnt vmcnt(4)" ::: "memory");
    asm volatile("s_barrier" ::: "memory");
    __builtin_amdgcn_sched_barrier(0);

#pragma unroll 1
    for (int kt0 = 0; kt0 < NSTEPS - 4; kt0 += 4) {
        KSTEP(S0, S2, kt0 + 2, true, 4);
        KSTEP(S1, S3, kt0 + 3, true, 4);
        KSTEP(S2, S0, kt0 + 4, true, 4);
        KSTEP(S3, S1, kt0 + 5, true, 4);
    }
    KSTEP(S0, S2, NSTEPS - 2, true, 4);
    KSTEP(S1, S3, NSTEPS - 1, true, 4);
    KSTEP(S2, S0, 0, false, 0);
    KSTEP(S3, S0, 0, false, 0);
#undef KSTEP

    const int g = lane >> 4, c15 = lane & 15;
    float bc[8];
#pragma unroll
    for (int n = 0; n < 8; ++n) bc[n] = brn[col0 + wc * 128 + n * 16 + c15];

    if constexpr (EPI == 0) {
#pragma unroll
        for (int m = 0; m < 4; ++m)
#pragma unroll
            for (int rr = 0; rr < 4; ++rr) {
                const int grow = row0 + wr * 64 + m * 16 + g * 4 + rr;
                const float ar = arn[grow];
                float mx = -1e30f; int mi = 0; float se = 0.f;
#pragma unroll
                for (int n = 0; n < 8; ++n) {
                    float lg = acc[m][n][rr] * ar * bc[n];
                    int gcol = col0 + wc * 128 + n * 16 + c15;
                    se += __expf(lg);
                    if (lg > mx || (lg == mx && gcol < mi)) { mx = lg; mi = gcol; }
                }
#pragma unroll
                for (int off = 1; off < 16; off <<= 1) {
                    float om = __shfl_xor(mx, off, 16);
                    int   oi = __shfl_xor(mi, off, 16);
                    float os = __shfl_xor(se, off, 16);
                    se += os;
                    if (om > mx || (om == mx && oi < mi)) { mx = om; mi = oi; }
                }
                if (c15 == 0) {
                    atomicMax(packed + grow, pack_max(mx, (unsigned)mi));
                    atomicAdd(&ssum[grow], se);
                }
            }
    } else {
        float cp[8] = {0.f, 0.f, 0.f, 0.f, 0.f, 0.f, 0.f, 0.f};
#pragma unroll
        for (int m = 0; m < 4; ++m)
#pragma unroll
            for (int rr = 0; rr < 4; ++rr) {
                const int grow = row0 + wr * 64 + m * 16 + g * 4 + rr;
                const float ar = arn[grow];
                const float si = 1.0f / ssum[grow];
#pragma unroll
                for (int n = 0; n < 8; ++n)
                    cp[n] += __expf(acc[m][n][rr] * ar * bc[n]) * si;
            }
#pragma unroll
        for (int n = 0; n < 8; ++n) {
            cp[n] += __shfl_xor(cp[n], 16);
            cp[n] += __shfl_xor(cp[n], 32);
        }
        float* sm = (float*)lds;
        if (g == 0) {
#pragma unroll
            for (int n = 0; n < 8; ++n) sm[wavei * 128 + n * 16 + c15] = cp[n];
        }
        __syncthreads();
        if (tid < 256) {
            int wcc = tid >> 7, j = tid & 127;
            float s = sm[(0 + wcc) * 128 + j] + sm[(2 + wcc) * 128 + j]
                    + sm[(4 + wcc) * 128 + j] + sm[(6 + wcc) * 128 + j];
            atomicAdd(&avgp[col0 + wcc * 128 + j], s);
        }
    }
}

// ---------------- fallback: fp32 VALU GEMM (proven round-1 path) ----------------
template <int PASS>
__global__ __launch_bounds__(256) void gemm_pass(
        const float* __restrict__ A, const float* __restrict__ B,
        const float* __restrict__ arn, const float* __restrict__ brn,
        unsigned long long* __restrict__ packed, float* __restrict__ ssum,
        float* __restrict__ avgp) {
    __shared__ __align__(16) float As[16][132];
    __shared__ __align__(16) float Bs[16][132];
    const int tid = threadIdx.x;
    const int tr = tid >> 4, tc = tid & 15;
    const int row0 = blockIdx.y * 128, col0 = blockIdx.x * 128;

    float acc[8][8] = {};
    const float4* A4 = reinterpret_cast<const float4*>(A);
    const float4* B4 = reinterpret_cast<const float4*>(B);

    for (int d0 = 0; d0 < DIM; d0 += 16) {
#pragma unroll
        for (int l = 0; l < 2; ++l) {
            int q = tid + l * 256;
            int r = q >> 2, dq = q & 3;
            float4 av = A4[(size_t)(row0 + r) * (DIM / 4) + (d0 >> 2) + dq];
            float4 bv = B4[(size_t)(col0 + r) * (DIM / 4) + (d0 >> 2) + dq];
            As[dq*4+0][r] = av.x; As[dq*4+1][r] = av.y; As[dq*4+2][r] = av.z; As[dq*4+3][r] = av.w;
            Bs[dq*4+0][r] = bv.x; Bs[dq*4+1][r] = bv.y; Bs[dq*4+2][r] = bv.z; Bs[dq*4+3][r] = bv.w;
        }
        __syncthreads();
#pragma unroll
        for (int dd = 0; dd < 16; ++dd) {
            float4 a0 = *reinterpret_cast<const float4*>(&As[dd][tr * 4]);
            float4 a1 = *reinterpret_cast<const float4*>(&As[dd][64 + tr * 4]);
            float4 b0 = *reinterpret_cast<const float4*>(&Bs[dd][tc * 4]);
            float4 b1 = *reinterpret_cast<const float4*>(&Bs[dd][64 + tc * 4]);
            float av[8] = {a0.x, a0.y, a0.z, a0.w, a1.x, a1.y, a1.z, a1.w};
            float bv[8] = {b0.x, b0.y, b0.z, b0.w, b1.x, b1.y, b1.z, b1.w};
#pragma unroll
            for (int i = 0; i < 8; ++i)
#pragma unroll
                for (int j = 0; j < 8; ++j)
                    acc[i][j] = fmaf(av[i], bv[j], acc[i][j]);
        }
        __syncthreads();
    }

    int rows[8], cols[8];
    float ar[8], bcv[8];
#pragma unroll
    for (int i = 0; i < 8; ++i) {
        rows[i] = (i < 4) ? (tr * 4 + i) : (64 + tr * 4 + i - 4);
        ar[i] = arn[row0 + rows[i]];
    }
#pragma unroll
    for (int j = 0; j < 8; ++j) {
        cols[j] = (j < 4) ? (tc * 4 + j) : (64 + tc * 4 + j - 4);
        bcv[j] = brn[col0 + cols[j]];
    }

    if constexpr (PASS == 1) {
#pragma unroll
        for (int i = 0; i < 8; ++i) {
            float m = -1e30f; int mi = 0; float se = 0.0f;
#pragma unroll
            for (int j = 0; j < 8; ++j) {
                float l = acc[i][j] * ar[i] * bcv[j];
                int c = col0 + cols[j];
                if (l > m || (l == m && c < mi)) { m = l; mi = c; }
                se += expf(l);
            }
#pragma unroll
            for (int off = 1; off < 16; off <<= 1) {
                float om = __shfl_xor(m, off, 16);
                int   oi = __shfl_xor(mi, off, 16);
                float os = __shfl_xor(se, off, 16);
                se += os;
                if (om > m || (om == m && oi < mi)) { m = om; mi = oi; }
            }
            if (tc == 0) {
                int grow = row0 + rows[i];
                atomicMax(packed + grow, pack_max(m, (unsigned)mi));
                atomicAdd(&ssum[grow], se);
            }
        }
    } else {
        float sinv[8];
#pragma unroll
        for (int i = 0; i < 8; ++i) sinv[i] = 1.0f / ssum[row0 + rows[i]];
        float cp[8] = {};
#pragma unroll
        for (int i = 0; i < 8; ++i)
#pragma unroll
            for (int j = 0; j < 8; ++j)
                cp[j] += expf(acc[i][j] * ar[i] * bcv[j]) * sinv[i];
        __syncthreads();
        float* red = &As[0][0];
#pragma unroll
        for (int j = 0; j < 8; ++j) red[tr * 128 + cols[j]] = cp[j];
        __syncthreads();
        if (tid < 128) {
            float s = 0.0f;
#pragma unroll
            for (int t = 0; t < 16; ++t) s += red[t * 128 + tid];
            atomicAdd(&avgp[col0 + tid], s);
        }
    }
}

// norm-only kernel for the fallback path
__global__ __launch_bounds__(256) void rownorm_only(const float* __restrict__ x,
                                                    float* __restrict__ outp,
                                                    const float* __restrict__ scale_ptr) {
    int lane = threadIdx.x & 63;
    int row  = blockIdx.x * 4 + (threadIdx.x >> 6);
    const float4* x4 = reinterpret_cast<const float4*>(x) + (size_t)row * (DIM / 4);
    float4 v0 = x4[lane];
    float4 v1 = x4[64 + lane];
    float s = v0.x*v0.x + v0.y*v0.y + v0.z*v0.z + v0.w*v0.w
            + v1.x*v1.x + v1.y*v1.y + v1.z*v1.z + v1.w*v1.w;
#pragma unroll
    for (int off = 32; off; off >>= 1) s += __shfl_xor(s, off);
    if (lane == 0) {
        float scale = scale_ptr ? scale_ptr[0] : 1.0f;
        outp[row] = scale / fmaxf(sqrtf(s), 1e-12f);
    }
}

// ---------------- output kernels ----------------
__global__ __launch_bounds__(256) void zq_kernel(const float* __restrict__ ze,
                                                 const float* __restrict__ emb,
                                                 const unsigned long long* __restrict__ packed,
                                                 const float* __restrict__ resw,
                                                 float* __restrict__ out) {
    int q = blockIdx.x * 256 + threadIdx.x;
    int n = q >> 7, d4 = q & 127;
    unsigned idx = ~(unsigned)(packed[n] & 0xFFFFFFFFull);
    float alpha = 1.0f / (1.0f + expf(-resw[0]));
    float4 e = reinterpret_cast<const float4*>(emb)[(size_t)idx * 128 + d4];
    float4 z = reinterpret_cast<const float4*>(ze)[(size_t)n * 128 + d4];
    float4 o;
    o.x = alpha * e.x + (1.0f - alpha) * z.x;
    o.y = alpha * e.y + (1.0f - alpha) * z.y;
    o.z = alpha * e.z + (1.0f - alpha) * z.z;
    o.w = alpha * e.w + (1.0f - alpha) * z.w;
    reinterpret_cast<float4*>(out)[(size_t)n * 128 + d4] = o;
    if (d4 == 0) out[ND_OUT + n] = (float)idx;
}

__global__ __launch_bounds__(256) void finalize_kernel(const float* __restrict__ avgp,
                                                       const float* __restrict__ resw,
                                                       float* __restrict__ out) {
    float acc = 0.0f;
    for (int k = threadIdx.x; k < K_CODES; k += 256) {
        float p = avgp[k] * (1.0f / (float)N_ROWS);
        acc += p * logf(p + 1e-10f);
    }
    __shared__ float red[4];
#pragma unroll
    for (int off = 32; off; off >>= 1) acc += __shfl_xor(acc, off);
    int lane = threadIdx.x & 63, wave = threadIdx.x >> 6;
    if (lane == 0) red[wave] = acc;
    __syncthreads();
    if (threadIdx.x == 0) {
        float s = red[0] + red[1] + red[2] + red[3];
        out[ND_OUT + N_ROWS]     = expf(-s);
        out[ND_OUT + N_ROWS + 1] = 1.0f / (1.0f + expf(-resw[0]));
    }
}

extern "C" void kernel_launch(void* const* d_in, const int* in_sizes, int n_in,
                              void* d_out, int out_size, void* d_ws, size_t ws_size,
                              hipStream_t stream) {
    const float* ze   = (const float*)d_in[0];
    const float* emb  = (const float*)d_in[1];
    const float* ls   = (const float*)d_in[2];
    const float* resw = (const float*)d_in[3];
    float* out = (float*)d_out;

    char* ws = (char*)d_ws;
    unsigned long long* packed = (unsigned long long*)(ws + WS_PACKED);
    float* ssum = (float*)(ws + WS_SSUM);
    float* avgp = (float*)(ws + WS_AVGP);
    float* arn  = (float*)(ws + WS_ARN);
    float* brn  = (float*)(ws + WS_BRN);

    hipMemsetAsync(d_ws, 0, 802816, stream);   // packed | ssum | avgp

    if (ws_size >= NEED_B) {
        ushort* planes = (ushort*)(ws + WS_PLANES);
        norm_split<<<N_ROWS / 4, 256, 0, stream>>>(ze, planes + PE_AH, planes + PE_AL, arn, ls);
        norm_split<<<K_CODES / 4, 256, 0, stream>>>(emb, planes + PE_BH, planes + PE_BL, brn, nullptr);

        // pass 1: exact 4-term compensated GEMM, single-barrier overlapped pipeline
        mfma4<<<4096, 512, 0, stream>>>(planes, arn, brn, packed, ssum);
        // pass 2: hi*hi only (avg_probs path), round-4 pipeline (proven)
        mfma3<2, 1><<<4096, 512, 0, stream>>>(planes, arn, brn, packed, ssum, avgp);
    } else {
        rownorm_only<<<N_ROWS / 4, 256, 0, stream>>>(ze, arn, ls);
        rownorm_only<<<K_CODES / 4, 256, 0, stream>>>(emb, brn, nullptr);
        dim3 grid(K_CODES / 128, N_ROWS / 128);
        gemm_pass<1><<<grid, 256, 0, stream>>>(ze, emb, arn, brn, packed, ssum, avgp);
        gemm_pass<2><<<grid, 256, 0, stream>>>(ze, emb, arn, brn, packed, ssum, avgp);
    }

    zq_kernel<<<(N_ROWS * (DIM / 4)) / 256, 256, 0, stream>>>(ze, emb, packed, resw, out);
    finalize_kernel<<<1, 256, 0, stream>>>(avgp, resw, out);
}

// Round 8
// 1462.394 us; speedup vs baseline: 1.1636x; 1.1636x over previous
//
#include <hip/hip_runtime.h>
#include <cstdint>
#include <cstddef>

// Problem constants (match reference)
#define N_ROWS 65536
#define K_CODES 4096
#define DIM 512
#define ND_OUT ((size_t)N_ROWS * DIM)   // 33554432

typedef __attribute__((ext_vector_type(8))) short  short8v;   // 8 x bf16 (4 VGPR)
typedef __attribute__((ext_vector_type(4))) float  f32x4;

// ---------------- d_ws layout (bytes) ----------------
#define WS_PACKED   0u            // u64[N]
#define WS_SSUM     524288u       // f32[N]
#define WS_AVGP     786432u       // f32[K]
#define WS_ARN      802816u       // f32[N]
#define WS_BRN      1064960u      // f32[K]
#define WS_PLANES   2097152ull    // bf16 planes: Ah | Al | Bh | Bl (contiguous)
#define SZ_APLANE   67108864ull   // N*512*2
#define SZ_BPLANE   4194304ull    // K*512*2
#define NEED_B      (WS_PLANES + 2*SZ_APLANE + 2*SZ_BPLANE)   // 144703488

// plane offsets in bf16 elements, relative to planes base
#define PE_AH 0
#define PE_AL 33554432
#define PE_BH 67108864
#define PE_BL 69206016

#define GLOAD_LDS16(gsrc, ldst) \
  __builtin_amdgcn_global_load_lds((const __attribute__((address_space(1))) void*)(gsrc), \
                                   (__attribute__((address_space(3))) void*)(ldst), 16, 0, 0)

__device__ inline unsigned long long pack_max(float v, unsigned idx) {
    unsigned u = __float_as_uint(v);
    u = (u & 0x80000000u) ? ~u : (u | 0x80000000u);
    return ((unsigned long long)u << 32) | (unsigned)(~idx);  // tie -> smaller idx wins
}

__device__ inline ushort bf16rn(float f) {
    unsigned u = __float_as_uint(f);
    u += 0x7FFFu + ((u >> 16) & 1u);
    return (ushort)(u >> 16);
}
__device__ inline float bf16f(ushort h) { return __uint_as_float((unsigned)h << 16); }

// ---------------- fused norm + hi/lo split (one wave per row) ----------------
__global__ __launch_bounds__(256) void norm_split(const float* __restrict__ x,
                                                  ushort* __restrict__ hi,
                                                  ushort* __restrict__ lo,
                                                  float* __restrict__ nrm,
                                                  const float* __restrict__ scale_ptr) {
    int lane = threadIdx.x & 63;
    int row  = blockIdx.x * 4 + (threadIdx.x >> 6);
    const float4* x4 = reinterpret_cast<const float4*>(x) + (size_t)row * (DIM / 4);
    float4 v0 = x4[lane];
    float4 v1 = x4[64 + lane];
    float s = v0.x*v0.x + v0.y*v0.y + v0.z*v0.z + v0.w*v0.w
            + v1.x*v1.x + v1.y*v1.y + v1.z*v1.z + v1.w*v1.w;
#pragma unroll
    for (int off = 32; off; off >>= 1) s += __shfl_xor(s, off);

    ushort4 h0, l0, h1, l1;
    h0.x = bf16rn(v0.x); l0.x = bf16rn(v0.x - bf16f(h0.x));
    h0.y = bf16rn(v0.y); l0.y = bf16rn(v0.y - bf16f(h0.y));
    h0.z = bf16rn(v0.z); l0.z = bf16rn(v0.z - bf16f(h0.z));
    h0.w = bf16rn(v0.w); l0.w = bf16rn(v0.w - bf16f(h0.w));
    h1.x = bf16rn(v1.x); l1.x = bf16rn(v1.x - bf16f(h1.x));
    h1.y = bf16rn(v1.y); l1.y = bf16rn(v1.y - bf16f(h1.y));
    h1.z = bf16rn(v1.z); l1.z = bf16rn(v1.z - bf16f(h1.z));
    h1.w = bf16rn(v1.w); l1.w = bf16rn(v1.w - bf16f(h1.w));
    ushort4* hi4 = reinterpret_cast<ushort4*>(hi) + (size_t)row * (DIM / 4);
    ushort4* lo4 = reinterpret_cast<ushort4*>(lo) + (size_t)row * (DIM / 4);
    hi4[lane] = h0; hi4[64 + lane] = h1;
    lo4[lane] = l0; lo4[64 + lane] = l1;

    if (lane == 0) {
        float scale = scale_ptr ? scale_ptr[0] : 1.0f;
        nrm[row] = scale / fmaxf(sqrtf(s), 1e-12f);
    }
}

// ---------------- PASS 1: full-reuse compensated GEMM, grouped-prefetch step ----------
// Tile 256x256, 512 thr = 8 waves (4 wr x 2 wc), wave-tile 64x128, BK=32 per K-step.
// LDS: 4 sub-slots x 32KB ring (2 steps of hi/lo pairs); 1 barrier/step (round-6 ledger).
// Register discipline: ah(16)+al(16) resident; B prefetched in 4-frag groups (16 VGPR),
// two groups ping-pong => max frag live = 64 VGPR (round 7's 96 spilled; this must not).
// Per step:
//   vmcnt(0) [retires stage(t-1), ~1 step old]; s_barrier
//   ds_read ah(4), al(4), G0=bh0(4); stage(t+1); ds_read G1=bh1(4)
//   lgkm(4)  -> MFMA ah*G0, al*G0 (32)   | ds_read G2=bl0 under it
//   lgkm(4)  -> MFMA ah*G1, al*G1 (32)   | ds_read G3=bl1 under it
//   lgkm(4)  -> MFMA ah*G2, al*G2 (32)
//   lgkm(0)  -> MFMA ah*G3, al*G3 (32)
__global__ __launch_bounds__(512, 2) void mfma4(
        const ushort* __restrict__ planes,
        const float* __restrict__ arn, const float* __restrict__ brn,
        unsigned long long* __restrict__ packed, float* __restrict__ ssum) {
    __shared__ __align__(16) char lds[131072];
    char* const R0 = lds;
    char* const R1 = lds + 32768;
    char* const R2 = lds + 65536;
    char* const R3 = lds + 98304;

    const int tid  = threadIdx.x;
    const int lane = tid & 63;
    const int wavei = __builtin_amdgcn_readfirstlane(tid >> 6);
    const int wr = wavei >> 1, wc = wavei & 1;
    const int r16 = lane & 15, kg = lane >> 4;

    // XCD swizzle (nwg=4096 %8==0)
    const int orig = blockIdx.x;
    const int swz  = (orig & 7) * 512 + (orig >> 3);
    const int row0 = (swz >> 4) * 256, col0 = (swz & 15) * 256;

    // staging: 4 units (1KB = 64 lanes x 16B) per wave per sub-slot
    size_t rowoff[4];
    int ldso[4];
    bool uA[4];
#pragma unroll
    for (int j = 0; j < 4; ++j) {
        int u = wavei * 4 + j;        // 0..31: units 0-15 = A, 16-31 = B
        bool a = (u < 16);
        int g0 = a ? row0 : col0;
        rowoff[j] = (size_t)(g0 + (u & 15) * 16 + r16) * DIM + kg * 8;
        ldso[j] = u * 1024;
        uA[j] = a;
    }

#define STAGE_HI(KK, DST)                                                              \
    { _Pragma("unroll")                                                                \
      for (int j = 0; j < 4; ++j)                                                      \
          GLOAD_LDS16(planes + (uA[j] ? PE_AH : PE_BH) + rowoff[j] + (KK),             \
                      (DST) + ldso[j]); }
#define STAGE_LO(KK, DST)                                                              \
    { _Pragma("unroll")                                                                \
      for (int j = 0; j < 4; ++j)                                                      \
          GLOAD_LDS16(planes + (uA[j] ? PE_AL : PE_BL) + rowoff[j] + (KK),             \
                      (DST) + ldso[j]); }

    f32x4 acc[4][8];
#pragma unroll
    for (int m = 0; m < 4; ++m)
#pragma unroll
        for (int n = 0; n < 8; ++n) acc[m][n] = f32x4{0.f, 0.f, 0.f, 0.f};

    // 16 MFMA: one A-set (4 frags) x one B-group (4 frags) into acc columns NB..NB+3
#define MFMA16(AV, BV, NB)                                                             \
    _Pragma("unroll")                                                                  \
    for (int m_ = 0; m_ < 4; ++m_)                                                     \
        _Pragma("unroll")                                                              \
        for (int n_ = 0; n_ < 4; ++n_)                                                 \
            acc[m_][(NB) + n_] = __builtin_amdgcn_mfma_f32_16x16x32_bf16(              \
                (AV)[m_], (BV)[n_], acc[m_][(NB) + n_], 0, 0, 0);

#define STEP(HI, LO, HI2, LO2, KNEXT, DOSTAGE)                                         \
    {                                                                                  \
        short8v ah_[4], al_[4], ga_[4], gb_[4];                                        \
        asm volatile("s_waitcnt vmcnt(0)" ::: "memory");                               \
        asm volatile("s_barrier" ::: "memory");                                        \
        __builtin_amdgcn_sched_barrier(0);                                             \
        _Pragma("unroll")                                                              \
        for (int m = 0; m < 4; ++m)                                                    \
            ah_[m] = *(const short8v*)((HI) + (wr * 4 + m) * 1024 + lane * 16);        \
        _Pragma("unroll")                                                              \
        for (int m = 0; m < 4; ++m)                                                    \
            al_[m] = *(const short8v*)((LO) + (wr * 4 + m) * 1024 + lane * 16);        \
        _Pragma("unroll")                                                              \
        for (int n = 0; n < 4; ++n)  /* G0 = bh[0:4] */                                \
            ga_[n] = *(const short8v*)((HI) + 16384 + (wc * 8 + n) * 1024 + lane * 16);\
        if (DOSTAGE) { STAGE_HI((KNEXT) * 32, HI2); STAGE_LO((KNEXT) * 32, LO2); }     \
        _Pragma("unroll")                                                              \
        for (int n = 0; n < 4; ++n)  /* G1 = bh[4:8] */                                \
            gb_[n] = *(const short8v*)((HI) + 16384 + (wc * 8 + 4 + n) * 1024 + lane * 16);\
        asm volatile("s_waitcnt lgkmcnt(4)" ::: "memory");  /* ah,al,G0 ready */       \
        __builtin_amdgcn_sched_barrier(0);                                             \
        __builtin_amdgcn_s_setprio(1);                                                 \
        MFMA16(ah_, ga_, 0);                                                           \
        MFMA16(al_, ga_, 0);                                                           \
        __builtin_amdgcn_s_setprio(0);                                                 \
        __builtin_amdgcn_sched_barrier(0);                                             \
        _Pragma("unroll")                                                              \
        for (int n = 0; n < 4; ++n)  /* G2 = bl[0:4] */                                \
            ga_[n] = *(const short8v*)((LO) + 16384 + (wc * 8 + n) * 1024 + lane * 16);\
        asm volatile("s_waitcnt lgkmcnt(4)" ::: "memory");  /* G1 ready */             \
        __builtin_amdgcn_sched_barrier(0);                                             \
        __builtin_amdgcn_s_setprio(1);                                                 \
        MFMA16(ah_, gb_, 4);                                                           \
        MFMA16(al_, gb_, 4);                                                           \
        __builtin_amdgcn_s_setprio(0);                                                 \
        __builtin_amdgcn_sched_barrier(0);                                             \
        _Pragma("unroll")                                                              \
        for (int n = 0; n < 4; ++n)  /* G3 = bl[4:8] */                                \
            gb_[n] = *(const short8v*)((LO) + 16384 + (wc * 8 + 4 + n) * 1024 + lane * 16);\
        asm volatile("s_waitcnt lgkmcnt(4)" ::: "memory");  /* G2 ready */             \
        __builtin_amdgcn_sched_barrier(0);                                             \
        __builtin_amdgcn_s_setprio(1);                                                 \
        MFMA16(ah_, ga_, 0);                                                           \
        MFMA16(al_, ga_, 0);                                                           \
        __builtin_amdgcn_s_setprio(0);                                                 \
        __builtin_amdgcn_sched_barrier(0);                                             \
        asm volatile("s_waitcnt lgkmcnt(0)" ::: "memory");  /* G3 ready */             \
        __builtin_amdgcn_sched_barrier(0);                                             \
        __builtin_amdgcn_s_setprio(1);                                                 \
        MFMA16(ah_, gb_, 4);                                                           \
        MFMA16(al_, gb_, 4);                                                           \
        __builtin_amdgcn_s_setprio(0);                                                 \
        __builtin_amdgcn_sched_barrier(0);                                             \
    }

    // prologue: stage step 0 into R0/R1 (one-time exposed latency at t=0)
    STAGE_HI(0, R0);
    STAGE_LO(0, R1);

#pragma unroll 1
    for (int t = 0; t < 14; t += 2) {
        STEP(R0, R1, R2, R3, t + 1, 1);   // even step: read pair{0,1}, stage pair{2,3}
        STEP(R2, R3, R0, R1, t + 2, 1);   // odd  step: read pair{2,3}, stage pair{0,1}
    }
    STEP(R0, R1, R2, R3, 15, 1);          // t=14: stages step 15 -> R2,R3
    STEP(R2, R3, R0, R1, 0, 0);           // t=15: no stage
#undef STEP
#undef MFMA16
#undef STAGE_HI
#undef STAGE_LO

    // ---------------- epilogue: argmax + sumexp ----------------
    const int g = lane >> 4, c15 = lane & 15;
    float bc[8];
#pragma unroll
    for (int n = 0; n < 8; ++n) bc[n] = brn[col0 + wc * 128 + n * 16 + c15];

#pragma unroll
    for (int m = 0; m < 4; ++m)
#pragma unroll
        for (int rr = 0; rr < 4; ++rr) {
            const int grow = row0 + wr * 64 + m * 16 + g * 4 + rr;
            const float ar = arn[grow];
            float mx = -1e30f; int mi = 0; float se = 0.f;
#pragma unroll
            for (int n = 0; n < 8; ++n) {
                float lg = acc[m][n][rr] * ar * bc[n];
                int gcol = col0 + wc * 128 + n * 16 + c15;
                se += __expf(lg);
                if (lg > mx || (lg == mx && gcol < mi)) { mx = lg; mi = gcol; }
            }
#pragma unroll
            for (int off = 1; off < 16; off <<= 1) {
                float om = __shfl_xor(mx, off, 16);
                int   oi = __shfl_xor(mi, off, 16);
                float os = __shfl_xor(se, off, 16);
                se += os;
                if (om > mx || (om == mx && oi < mi)) { mx = om; mi = oi; }
            }
            if (c15 == 0) {
                atomicMax(packed + grow, pack_max(mx, (unsigned)mi));
                atomicAdd(&ssum[grow], se);
            }
        }
}

// ---------------- PASS 2: hh-only counted-vmcnt 4-slot pipeline (round-4, proven) ----------------
template <int EPI, int NREG>
__global__ __launch_bounds__(512, 2) void mfma3(
        const ushort* __restrict__ planes,
        const float* __restrict__ arn, const float* __restrict__ brn,
        unsigned long long* __restrict__ packed, float* __restrict__ ssum,
        float* __restrict__ avgp) {
    constexpr int NSTEPS = NREG * 16;
    __shared__ __align__(16) char lds[131072];

    const int tid  = threadIdx.x;
    const int lane = tid & 63;
    const int wavei = __builtin_amdgcn_readfirstlane(tid >> 6);
    const int wr = wavei >> 1, wc = wavei & 1;
    const int r16 = lane & 15, kg = lane >> 4;

    const int orig = blockIdx.x;
    const int swz  = (orig & 7) * 512 + (orig >> 3);
    const int row0 = (swz >> 4) * 256, col0 = (swz & 15) * 256;

    size_t rowoff[4];
    int ldso[4];
    bool uA[4];
#pragma unroll
    for (int j = 0; j < 4; ++j) {
        int u = wavei * 4 + j;
        bool a = (u < 16);
        int g0 = a ? row0 : col0;
        rowoff[j] = (size_t)(g0 + (u & 15) * 16 + r16) * DIM + kg * 8;
        ldso[j] = u * 1024;
        uA[j] = a;
    }

    auto STAGE = [&](int ks, char* slot) {
        int rg  = (ks >> 4) & 3;
        int kk  = (ks & 15) * 32;
        int bA = (rg & 1) ? PE_AL : PE_AH;
        int bB = ((rg ^ (rg >> 1)) & 1) ? PE_BL : PE_BH;
#pragma unroll
        for (int j = 0; j < 4; ++j) {
            const ushort* src = planes + (uA[j] ? bA : bB) + kk + rowoff[j];
            GLOAD_LDS16(src, slot + ldso[j]);
        }
    };

    f32x4 acc[4][8];
#pragma unroll
    for (int m = 0; m < 4; ++m)
#pragma unroll
        for (int n = 0; n < 8; ++n) acc[m][n] = f32x4{0.f, 0.f, 0.f, 0.f};

    char* const S0 = lds;
    char* const S1 = lds + 32768;
    char* const S2 = lds + 65536;
    char* const S3 = lds + 98304;

#define KSTEP(CUR, NXT, KS, DO_STAGE, VMC)                                              \
    do {                                                                                \
        short8v a_[4], b_[8];                                                           \
        _Pragma("unroll")                                                               \
        for (int m = 0; m < 4; ++m)                                                     \
            a_[m] = *(const short8v*)((CUR) + (wr * 4 + m) * 1024 + lane * 16);         \
        _Pragma("unroll")                                                               \
        for (int n = 0; n < 8; ++n)                                                     \
            b_[n] = *(const short8v*)((CUR) + 16384 + (wc * 8 + n) * 1024 + lane * 16); \
        asm volatile("s_waitcnt lgkmcnt(0)" ::: "memory");                              \
        if (DO_STAGE) STAGE((KS), (NXT));                                               \
        asm volatile("s_waitcnt vmcnt(" #VMC ")" ::: "memory");                         \
        asm volatile("s_barrier" ::: "memory");                                         \
        __builtin_amdgcn_sched_barrier(0);                                              \
        __builtin_amdgcn_s_setprio(1);                                                  \
        _Pragma("unroll")                                                               \
        for (int m = 0; m < 4; ++m)                                                     \
            _Pragma("unroll")                                                           \
            for (int n = 0; n < 8; ++n)                                                 \
                acc[m][n] = __builtin_amdgcn_mfma_f32_16x16x32_bf16(a_[m], b_[n],       \
                                                                    acc[m][n], 0, 0, 0);\
        __builtin_amdgcn_s_setprio(0);                                                  \
        __builtin_amdgcn_sched_barrier(0);                                              \
    } while (0)

    STAGE(0, S0);
    STAGE(1, S1);
    asm volatile("s_waitcnt vmcnt(4)" ::: "memory");
    asm volatile("s_barrier" ::: "memory");
    __builtin_amdgcn_sched_barrier(0);

#pragma unroll 1
    for (int kt0 = 0; kt0 < NSTEPS - 4; kt0 += 4) {
        KSTEP(S0, S2, kt0 + 2, true, 4);
        KSTEP(S1, S3, kt0 + 3, true, 4);
        KSTEP(S2, S0, kt0 + 4, true, 4);
        KSTEP(S3, S1, kt0 + 5, true, 4);
    }
    KSTEP(S0, S2, NSTEPS - 2, true, 4);
    KSTEP(S1, S3, NSTEPS - 1, true, 4);
    KSTEP(S2, S0, 0, false, 0);
    KSTEP(S3, S0, 0, false, 0);
#undef KSTEP

    const int g = lane >> 4, c15 = lane & 15;
    float bc[8];
#pragma unroll
    for (int n = 0; n < 8; ++n) bc[n] = brn[col0 + wc * 128 + n * 16 + c15];

    if constexpr (EPI == 0) {
#pragma unroll
        for (int m = 0; m < 4; ++m)
#pragma unroll
            for (int rr = 0; rr < 4; ++rr) {
                const int grow = row0 + wr * 64 + m * 16 + g * 4 + rr;
                const float ar = arn[grow];
                float mx = -1e30f; int mi = 0; float se = 0.f;
#pragma unroll
                for (int n = 0; n < 8; ++n) {
                    float lg = acc[m][n][rr] * ar * bc[n];
                    int gcol = col0 + wc * 128 + n * 16 + c15;
                    se += __expf(lg);
                    if (lg > mx || (lg == mx && gcol < mi)) { mx = lg; mi = gcol; }
                }
#pragma unroll
                for (int off = 1; off < 16; off <<= 1) {
                    float om = __shfl_xor(mx, off, 16);
                    int   oi = __shfl_xor(mi, off, 16);
                    float os = __shfl_xor(se, off, 16);
                    se += os;
                    if (om > mx || (om == mx && oi < mi)) { mx = om; mi = oi; }
                }
                if (c15 == 0) {
                    atomicMax(packed + grow, pack_max(mx, (unsigned)mi));
                    atomicAdd(&ssum[grow], se);
                }
            }
    } else {
        float cp[8] = {0.f, 0.f, 0.f, 0.f, 0.f, 0.f, 0.f, 0.f};
#pragma unroll
        for (int m = 0; m < 4; ++m)
#pragma unroll
            for (int rr = 0; rr < 4; ++rr) {
                const int grow = row0 + wr * 64 + m * 16 + g * 4 + rr;
                const float ar = arn[grow];
                const float si = 1.0f / ssum[grow];
#pragma unroll
                for (int n = 0; n < 8; ++n)
                    cp[n] += __expf(acc[m][n][rr] * ar * bc[n]) * si;
            }
#pragma unroll
        for (int n = 0; n < 8; ++n) {
            cp[n] += __shfl_xor(cp[n], 16);
            cp[n] += __shfl_xor(cp[n], 32);
        }
        float* sm = (float*)lds;
        if (g == 0) {
#pragma unroll
            for (int n = 0; n < 8; ++n) sm[wavei * 128 + n * 16 + c15] = cp[n];
        }
        __syncthreads();
        if (tid < 256) {
            int wcc = tid >> 7, j = tid & 127;
            float s = sm[(0 + wcc) * 128 + j] + sm[(2 + wcc) * 128 + j]
                    + sm[(4 + wcc) * 128 + j] + sm[(6 + wcc) * 128 + j];
            atomicAdd(&avgp[col0 + wcc * 128 + j], s);
        }
    }
}

// ---------------- fallback: fp32 VALU GEMM (proven round-1 path) ----------------
template <int PASS>
__global__ __launch_bounds__(256) void gemm_pass(
        const float* __restrict__ A, const float* __restrict__ B,
        const float* __restrict__ arn, const float* __restrict__ brn,
        unsigned long long* __restrict__ packed, float* __restrict__ ssum,
        float* __restrict__ avgp) {
    __shared__ __align__(16) float As[16][132];
    __shared__ __align__(16) float Bs[16][132];
    const int tid = threadIdx.x;
    const int tr = tid >> 4, tc = tid & 15;
    const int row0 = blockIdx.y * 128, col0 = blockIdx.x * 128;

    float acc[8][8] = {};
    const float4* A4 = reinterpret_cast<const float4*>(A);
    const float4* B4 = reinterpret_cast<const float4*>(B);

    for (int d0 = 0; d0 < DIM; d0 += 16) {
#pragma unroll
        for (int l = 0; l < 2; ++l) {
            int q = tid + l * 256;
            int r = q >> 2, dq = q & 3;
            float4 av = A4[(size_t)(row0 + r) * (DIM / 4) + (d0 >> 2) + dq];
            float4 bv = B4[(size_t)(col0 + r) * (DIM / 4) + (d0 >> 2) + dq];
            As[dq*4+0][r] = av.x; As[dq*4+1][r] = av.y; As[dq*4+2][r] = av.z; As[dq*4+3][r] = av.w;
            Bs[dq*4+0][r] = bv.x; Bs[dq*4+1][r] = bv.y; Bs[dq*4+2][r] = bv.z; Bs[dq*4+3][r] = bv.w;
        }
        __syncthreads();
#pragma unroll
        for (int dd = 0; dd < 16; ++dd) {
            float4 a0 = *reinterpret_cast<const float4*>(&As[dd][tr * 4]);
            float4 a1 = *reinterpret_cast<const float4*>(&As[dd][64 + tr * 4]);
            float4 b0 = *reinterpret_cast<const float4*>(&Bs[dd][tc * 4]);
            float4 b1 = *reinterpret_cast<const float4*>(&Bs[dd][64 + tc * 4]);
            float av[8] = {a0.x, a0.y, a0.z, a0.w, a1.x, a1.y, a1.z, a1.w};
            float bv[8] = {b0.x, b0.y, b0.z, b0.w, b1.x, b1.y, b1.z, b1.w};
#pragma unroll
            for (int i = 0; i < 8; ++i)
#pragma unroll
                for (int j = 0; j < 8; ++j)
                    acc[i][j] = fmaf(av[i], bv[j], acc[i][j]);
        }
        __syncthreads();
    }

    int rows[8], cols[8];
    float ar[8], bcv[8];
#pragma unroll
    for (int i = 0; i < 8; ++i) {
        rows[i] = (i < 4) ? (tr * 4 + i) : (64 + tr * 4 + i - 4);
        ar[i] = arn[row0 + rows[i]];
    }
#pragma unroll
    for (int j = 0; j < 8; ++j) {
        cols[j] = (j < 4) ? (tc * 4 + j) : (64 + tc * 4 + j - 4);
        bcv[j] = brn[col0 + cols[j]];
    }

    if constexpr (PASS == 1) {
#pragma unroll
        for (int i = 0; i < 8; ++i) {
            float m = -1e30f; int mi = 0; float se = 0.0f;
#pragma unroll
            for (int j = 0; j < 8; ++j) {
                float l = acc[i][j] * ar[i] * bcv[j];
                int c = col0 + cols[j];
                if (l > m || (l == m && c < mi)) { m = l; mi = c; }
                se += expf(l);
            }
#pragma unroll
            for (int off = 1; off < 16; off <<= 1) {
                float om = __shfl_xor(m, off, 16);
                int   oi = __shfl_xor(mi, off, 16);
                float os = __shfl_xor(se, off, 16);
                se += os;
                if (om > m || (om == m && oi < mi)) { m = om; mi = oi; }
            }
            if (tc == 0) {
                int grow = row0 + rows[i];
                atomicMax(packed + grow, pack_max(m, (unsigned)mi));
                atomicAdd(&ssum[grow], se);
            }
        }
    } else {
        float sinv[8];
#pragma unroll
        for (int i = 0; i < 8; ++i) sinv[i] = 1.0f / ssum[row0 + rows[i]];
        float cp[8] = {};
#pragma unroll
        for (int i = 0; i < 8; ++i)
#pragma unroll
            for (int j = 0; j < 8; ++j)
                cp[j] += expf(acc[i][j] * ar[i] * bcv[j]) * sinv[i];
        __syncthreads();
        float* red = &As[0][0];
#pragma unroll
        for (int j = 0; j < 8; ++j) red[tr * 128 + cols[j]] = cp[j];
        __syncthreads();
        if (tid < 128) {
            float s = 0.0f;
#pragma unroll
            for (int t = 0; t < 16; ++t) s += red[t * 128 + tid];
            atomicAdd(&avgp[col0 + tid], s);
        }
    }
}

// norm-only kernel for the fallback path
__global__ __launch_bounds__(256) void rownorm_only(const float* __restrict__ x,
                                                    float* __restrict__ outp,
                                                    const float* __restrict__ scale_ptr) {
    int lane = threadIdx.x & 63;
    int row  = blockIdx.x * 4 + (threadIdx.x >> 6);
    const float4* x4 = reinterpret_cast<const float4*>(x) + (size_t)row * (DIM / 4);
    float4 v0 = x4[lane];
    float4 v1 = x4[64 + lane];
    float s = v0.x*v0.x + v0.y*v0.y + v0.z*v0.z + v0.w*v0.w
            + v1.x*v1.x + v1.y*v1.y + v1.z*v1.z + v1.w*v1.w;
#pragma unroll
    for (int off = 32; off; off >>= 1) s += __shfl_xor(s, off);
    if (lane == 0) {
        float scale = scale_ptr ? scale_ptr[0] : 1.0f;
        outp[row] = scale / fmaxf(sqrtf(s), 1e-12f);
    }
}

// ---------------- output kernels ----------------
__global__ __launch_bounds__(256) void zq_kernel(const float* __restrict__ ze,
                                                 const float* __restrict__ emb,
                                                 const unsigned long long* __restrict__ packed,
                                                 const float* __restrict__ resw,
                                                 float* __restrict__ out) {
    int q = blockIdx.x * 256 + threadIdx.x;
    int n = q >> 7, d4 = q & 127;
    unsigned idx = ~(unsigned)(packed[n] & 0xFFFFFFFFull);
    float alpha = 1.0f / (1.0f + expf(-resw[0]));
    float4 e = reinterpret_cast<const float4*>(emb)[(size_t)idx * 128 + d4];
    float4 z = reinterpret_cast<const float4*>(ze)[(size_t)n * 128 + d4];
    float4 o;
    o.x = alpha * e.x + (1.0f - alpha) * z.x;
    o.y = alpha * e.y + (1.0f - alpha) * z.y;
    o.z = alpha * e.z + (1.0f - alpha) * z.z;
    o.w = alpha * e.w + (1.0f - alpha) * z.w;
    reinterpret_cast<float4*>(out)[(size_t)n * 128 + d4] = o;
    if (d4 == 0) out[ND_OUT + n] = (float)idx;
}

__global__ __launch_bounds__(256) void finalize_kernel(const float* __restrict__ avgp,
                                                       const float* __restrict__ resw,
                                                       float* __restrict__ out) {
    float acc = 0.0f;
    for (int k = threadIdx.x; k < K_CODES; k += 256) {
        float p = avgp[k] * (1.0f / (float)N_ROWS);
        acc += p * logf(p + 1e-10f);
    }
    __shared__ float red[4];
#pragma unroll
    for (int off = 32; off; off >>= 1) acc += __shfl_xor(acc, off);
    int lane = threadIdx.x & 63, wave = threadIdx.x >> 6;
    if (lane == 0) red[wave] = acc;
    __syncthreads();
    if (threadIdx.x == 0) {
        float s = red[0] + red[1] + red[2] + red[3];
        out[ND_OUT + N_ROWS]     = expf(-s);
        out[ND_OUT + N_ROWS + 1] = 1.0f / (1.0f + expf(-resw[0]));
    }
}

extern "C" void kernel_launch(void* const* d_in, const int* in_sizes, int n_in,
                              void* d_out, int out_size, void* d_ws, size_t ws_size,
                              hipStream_t stream) {
    const float* ze   = (const float*)d_in[0];
    const float* emb  = (const float*)d_in[1];
    const float* ls   = (const float*)d_in[2];
    const float* resw = (const float*)d_in[3];
    float* out = (float*)d_out;

    char* ws = (char*)d_ws;
    unsigned long long* packed = (unsigned long long*)(ws + WS_PACKED);
    float* ssum = (float*)(ws + WS_SSUM);
    float* avgp = (float*)(ws + WS_AVGP);
    float* arn  = (float*)(ws + WS_ARN);
    float* brn  = (float*)(ws + WS_BRN);

    hipMemsetAsync(d_ws, 0, 802816, stream);   // packed | ssum | avgp

    if (ws_size >= NEED_B) {
        ushort* planes = (ushort*)(ws + WS_PLANES);
        norm_split<<<N_ROWS / 4, 256, 0, stream>>>(ze, planes + PE_AH, planes + PE_AL, arn, ls);
        norm_split<<<K_CODES / 4, 256, 0, stream>>>(emb, planes + PE_BH, planes + PE_BL, brn, nullptr);

        // pass 1: exact 4-term compensated GEMM, grouped-prefetch single-barrier pipeline
        mfma4<<<4096, 512, 0, stream>>>(planes, arn, brn, packed, ssum);
        // pass 2: hi*hi only (avg_probs path), round-4 pipeline (proven)
        mfma3<2, 1><<<4096, 512, 0, stream>>>(planes, arn, brn, packed, ssum, avgp);
    } else {
        rownorm_only<<<N_ROWS / 4, 256, 0, stream>>>(ze, arn, ls);
        rownorm_only<<<K_CODES / 4, 256, 0, stream>>>(emb, brn, nullptr);
        dim3 grid(K_CODES / 128, N_ROWS / 128);
        gemm_pass<1><<<grid, 256, 0, stream>>>(ze, emb, arn, brn, packed, ssum, avgp);
        gemm_pass<2><<<grid, 256, 0, stream>>>(ze, emb, arn, brn, packed, ssum, avgp);
    }

    zq_kernel<<<(N_ROWS * (DIM / 4)) / 256, 256, 0, stream>>>(ze, emb, packed, resw, out);
    finalize_kernel<<<1, 256, 0, stream>>>(avgp, resw, out);
}